// Round 4
// baseline (3483.412 us; speedup 1.0000x reference)
//
#include <hip/hip_runtime.h>
#include <math.h>

// Problem constants
#define BB 8
#define NN 16384      // H*W = 128*128
#define CCH 256       // input channels
#define OCH 512       // conv output channels = INNER
#define IMG 128

typedef float4 f4;
typedef _Float16 half8 __attribute__((ext_vector_type(8)));
typedef float floatx4 __attribute__((ext_vector_type(4)));

__device__ __forceinline__ f4 ldg4(const float* p) { return *(const f4*)p; }

// async global->LDS, 16B per lane; LDS dest = wave-uniform base + lane*16
__device__ __forceinline__ void gl16(const _Float16* g, const _Float16* l) {
  __builtin_amdgcn_global_load_lds(
      (const __attribute__((address_space(1))) void*)g,
      (__attribute__((address_space(3))) void*)l, 16, 0, 0);
}

// ---------------------------------------------------------------------------
// pad_split: x fp32 [8][128][128][256] -> zero-haloed fp16 hi/lo [8][130][130][256]
// hi = f16(x), lo = f16(x - hi). Halo rows/cols written as zeros every call.
// ---------------------------------------------------------------------------
__global__ __launch_bounds__(256) void pad_split(const float* __restrict__ x,
                                                 _Float16* __restrict__ xh,
                                                 _Float16* __restrict__ xl) {
  int tid = blockIdx.x * 256 + threadIdx.x;   // 8*130*130*32 = 4,326,400 exact
  int c8 = tid & 31;
  int p = tid >> 5;
  int xcol = p % 130;
  int p2 = p / 130;
  int y = p2 % 130;
  int b = p2 / 130;
  half8 hv, lv;
#pragma unroll
  for (int j = 0; j < 8; ++j) { hv[j] = (_Float16)0.f; lv[j] = (_Float16)0.f; }
  if (y >= 1 && y <= 128 && xcol >= 1 && xcol <= 128) {
    const float* src = x + ((size_t)(b * 128 + y - 1) * 128 + (xcol - 1)) * 256 + c8 * 8;
    f4 v0 = ldg4(src);
    f4 v1 = ldg4(src + 4);
    float vv[8] = {v0.x, v0.y, v0.z, v0.w, v1.x, v1.y, v1.z, v1.w};
#pragma unroll
    for (int j = 0; j < 8; ++j) {
      _Float16 h = (_Float16)vv[j];
      hv[j] = h;
      lv[j] = (_Float16)(vv[j] - (float)h);
    }
  }
  size_t dst = (size_t)p * 256 + c8 * 8;
  *(half8*)(xh + dst) = hv;
  *(half8*)(xl + dst) = lv;
}

// ---------------------------------------------------------------------------
// wsplit: conv_w fp32 [512][256][3][3] -> fp16 hi/lo Bt[tap][o][c] (o-major rows)
// ---------------------------------------------------------------------------
__global__ __launch_bounds__(256) void wsplit(const float* __restrict__ cw,
                                              _Float16* __restrict__ wh,
                                              _Float16* __restrict__ wl) {
  int tid = blockIdx.x * 256 + threadIdx.x;   // 9*512*32 = 147,456 exact
  int c8 = tid & 31;
  int o = (tid >> 5) & 511;
  int tap = tid >> 14;
  half8 hv, lv;
#pragma unroll
  for (int j = 0; j < 8; ++j) {
    float v = cw[(size_t)o * 2304 + (c8 * 8 + j) * 9 + tap];
    _Float16 h = (_Float16)v;
    hv[j] = h;
    lv[j] = (_Float16)(v - (float)h);
  }
  size_t dst = ((size_t)tap * 512 + o) * 256 + c8 * 8;
  *(half8*)(wh + dst) = hv;
  *(half8*)(wl + dst) = lv;
}

// ---------------------------------------------------------------------------
// conv_mfma v4: 3x3 SAME conv as implicit GEMM via fp16x2-split MFMA.
// Block: 128 pixels x 128 outch, 512 THREADS = 8 waves (4M x 2N), each wave
// a 32x64 output sub-tile (2x4 tiles of 16x16x32). K = 9 taps x 256 ch,
// BK=32 -> 72 K-steps.
//
// Round-3 post-mortem: depth-2/96KB gave 1 block/CU = 1 wave/SIMD -> every
// stall exposed; MfmaUtil pinned ~30% across v1/v2/v3. The binding resource
// is WAVES PER SIMD, not pipeline depth. v4: 2 buffers (64KB) -> 2 blocks/CU
// co-resident = 16 waves/CU = 4 waves/SIMD. Per-wave serial chain halves
// (12 ds_read_b128, 24 MFMA, 4 gl16 per K-step); two asynchronously-phased
// blocks per CU hide each other's vmcnt/barrier drains (m114 mechanism), and
// 2 waves/SIMD per block cover each other's lgkm waits.
// Schedule per K-step (proven m248 2-phase shape):
//   stage(t+1)->buf^1; ds_read buf; setprio(1); 24 MFMA; setprio(0);
//   sched_barrier(0); vmcnt(0); s_barrier      -- ONE barrier per K-step.
// Staging: wave w owns slot w (k8=w>>1, rows (w&1)*64+lane) of each of the
// 4 matrices (AH AL BH BL) -> same LDS layout as v2/v3 (verified passing).
// MFMA term order hh*8, lh*8, hl*8: per-acc add order unchanged -> bitwise-
// identical result. XCD-chunked swizzle (T1) kept (FETCH -7.6x in round 1).
// ---------------------------------------------------------------------------
__global__ __launch_bounds__(512, 4) void conv_mfma(const _Float16* __restrict__ xph,
                                                    const _Float16* __restrict__ xpl,
                                                    const _Float16* __restrict__ wh,
                                                    const _Float16* __restrict__ wl,
                                                    const float* __restrict__ cb,
                                                    float* __restrict__ xc) {
  __shared__ __align__(16) _Float16 sm[32768];  // 64KB: 2 buffers x 16384 halfs
  const int t = threadIdx.x;
  const int w = t >> 6, lane = t & 63;          // w = 0..7
  // XCD-chunked swizzle: nwg=4096, 8 XCDs, 512 blocks/XCD (= one image each)
  const int id = blockIdx.x;
  const int swz = (id & 7) * 512 + (id >> 3);
  const int obase = (swz & 3) * 128;
  const int p = swz >> 2;             // 0..1023
  const int bi = p >> 7, yy = p & 127;
  const int wm = (w & 3) * 32, wn = (w >> 2) * 64;

  floatx4 acc[2][4];
#pragma unroll
  for (int i = 0; i < 2; ++i)
#pragma unroll
    for (int j = 0; j < 4; ++j) acc[i][j] = (floatx4){0.f, 0.f, 0.f, 0.f};

  // staging: wave w owns slot w (of 8) per matrix; slot = 64 lanes x 16B
  const int loff = ((w & 1) * 64 + lane) * 256 + (w >> 1) * 8;  // global (halfs)
  const int ldst = w * 512;                                      // LDS (halfs)

  // issue the 4 global_load_lds for K-step `it` into buffer at smb
  auto stage = [&](int it, _Float16* smb) {
    const int tap = it >> 3;
    const int dy = (tap * 11) >> 5;   // tap/3 for tap in [0,9)
    const int dx = tap - dy * 3;
    const int c0 = (it & 7) * 32;
    const size_t ab = (size_t)((bi * 130 + yy + dy) * 130 + dx) * 256 + c0 + loff;
    const size_t bb = (size_t)(tap * 512 + obase) * 256 + c0 + loff;
    gl16(xph + ab, smb + ldst);
    gl16(xpl + ab, smb + 4096 + ldst);
    gl16(wh + bb, smb + 8192 + ldst);
    gl16(wl + bb, smb + 12288 + ldst);
  };

  const int kq = (lane >> 4) * 1024;      // k8 * 128 * 8 halfs
  const int ar = (wm + (lane & 15)) * 8;
  const int br = (wn + (lane & 15)) * 8;

  // prologue: fill buffer 0
  stage(0, sm);
  asm volatile("s_waitcnt vmcnt(0)" ::: "memory");
  __builtin_amdgcn_s_barrier();

#pragma unroll 2
  for (int it = 0; it < 72; ++it) {
    _Float16* smb = sm + (it & 1) * 16384;
    if (it < 71) stage(it + 1, sm + ((it + 1) & 1) * 16384);  // prefetch -> other buf

    half8 ah[2], al[2], bh[4], bl[4];
#pragma unroll
    for (int mt = 0; mt < 2; ++mt) {
      ah[mt] = *(const half8*)&smb[kq + ar + mt * 128];
      al[mt] = *(const half8*)&smb[4096 + kq + ar + mt * 128];
    }
#pragma unroll
    for (int nt = 0; nt < 4; ++nt) {
      bh[nt] = *(const half8*)&smb[8192 + kq + br + nt * 128];
      bl[nt] = *(const half8*)&smb[12288 + kq + br + nt * 128];
    }

    __builtin_amdgcn_s_setprio(1);
#pragma unroll
    for (int mt = 0; mt < 2; ++mt)
#pragma unroll
      for (int nt = 0; nt < 4; ++nt)
        acc[mt][nt] = __builtin_amdgcn_mfma_f32_16x16x32_f16(ah[mt], bh[nt], acc[mt][nt], 0, 0, 0);
#pragma unroll
    for (int mt = 0; mt < 2; ++mt)
#pragma unroll
      for (int nt = 0; nt < 4; ++nt)
        acc[mt][nt] = __builtin_amdgcn_mfma_f32_16x16x32_f16(al[mt], bh[nt], acc[mt][nt], 0, 0, 0);
#pragma unroll
    for (int mt = 0; mt < 2; ++mt)
#pragma unroll
      for (int nt = 0; nt < 4; ++nt)
        acc[mt][nt] = __builtin_amdgcn_mfma_f32_16x16x32_f16(ah[mt], bl[nt], acc[mt][nt], 0, 0, 0);
    __builtin_amdgcn_s_setprio(0);
    // keep MFMAs + their lgkm waits ahead of the barrier; then require the
    // prefetched tile to have landed before any wave proceeds.
    __builtin_amdgcn_sched_barrier(0);
    asm volatile("s_waitcnt vmcnt(0)" ::: "memory");
    __builtin_amdgcn_s_barrier();
  }

  // epilogue: C/D layout col=lane&15, row=(lane>>4)*4+reg
  const int col = lane & 15;
  const int qr = (lane >> 4) * 4;
#pragma unroll
  for (int nt = 0; nt < 4; ++nt) {
    const int och = obase + wn + nt * 16 + col;
    const float bias = cb[och];
#pragma unroll
    for (int mt = 0; mt < 2; ++mt)
#pragma unroll
      for (int r = 0; r < 4; ++r) {
        int m = wm + mt * 16 + qr + r;
        xc[((size_t)bi * NN + (size_t)yy * IMG + m) * OCH + och] = acc[mt][nt][r] + bias;
      }
  }
}

// ---------------------------------------------------------------------------
// Kernel B: fused K/V projection + kv accumulation (never materializes K,V).
// ---------------------------------------------------------------------------
__global__ __launch_bounds__(256) void bkern(const float* __restrict__ xc,
                                             const float* __restrict__ Wk,
                                             const float* __restrict__ Wv,
                                             float* __restrict__ P,
                                             float* __restrict__ PS) {
  __shared__ float wkT[4096];      // [d][c] = Wk[c][d]
  __shared__ float wvT[4096];
  __shared__ float red[64 * 65];   // block reduce, +1 pad
  __shared__ float Sred[64];
  const int t = threadIdx.x;
  const int bh = blockIdx.x >> 3;
  const int sp = blockIdx.x & 7;
  const int b = bh >> 3, h = bh & 7;
  {
    int d4 = (t & 15) * 4;
#pragma unroll
    for (int p = 0; p < 4; ++p) {
      int kr = (t >> 4) + p * 16;
      f4 wk = ldg4(Wk + kr * 64 + d4);
      f4 wv = ldg4(Wv + kr * 64 + d4);
      wkT[(d4 + 0) * 64 + kr] = wk.x; wkT[(d4 + 1) * 64 + kr] = wk.y;
      wkT[(d4 + 2) * 64 + kr] = wk.z; wkT[(d4 + 3) * 64 + kr] = wk.w;
      wvT[(d4 + 0) * 64 + kr] = wv.x; wvT[(d4 + 1) * 64 + kr] = wv.y;
      wvT[(d4 + 2) * 64 + kr] = wv.z; wvT[(d4 + 3) * 64 + kr] = wv.w;
    }
  }
  __syncthreads();
  const int lane = t & 63, w = t >> 6;
  float macc[64];
#pragma unroll
  for (int d = 0; d < 64; ++d) macc[d] = 0.f;
  float ssum = 0.f;
  const int nbase = sp * 2048 + w * 512;
  const float* xrow = xc + (size_t)(b * NN + nbase) * OCH + h * 64 + lane;
  for (int r = 0; r < 512; ++r) {
    float xv = *xrow;
    xrow += OCH;
    int xi = __float_as_int(xv);
    float klog = 0.f, vv = 0.f;
#pragma unroll
    for (int d = 0; d < 64; ++d) {
      float xd = __int_as_float(__builtin_amdgcn_readlane(xi, d));
      klog = fmaf(xd, wkT[d * 64 + lane], klog);
      vv = fmaf(xd, wvT[d * 64 + lane], vv);
    }
    float ek = expf(klog);
    ssum += ek;
    int ei = __float_as_int(ek);
#pragma unroll
    for (int d = 0; d < 64; ++d) {
      float ekd = __int_as_float(__builtin_amdgcn_readlane(ei, d));
      macc[d] = fmaf(ekd, vv, macc[d]);
    }
  }
  for (int ww = 0; ww < 4; ++ww) {
    if (w == ww) {
      if (ww == 0) {
#pragma unroll
        for (int d = 0; d < 64; ++d) red[d * 65 + lane] = macc[d];
        Sred[lane] = ssum;
      } else {
#pragma unroll
        for (int d = 0; d < 64; ++d) red[d * 65 + lane] += macc[d];
        Sred[lane] += ssum;
      }
    }
    __syncthreads();
  }
  float* Pp = P + (size_t)blockIdx.x * 4096;
#pragma unroll
  for (int e = 0; e < 16; ++e) {
    int idx = t + e * 256;
    Pp[idx] = red[(idx >> 6) * 65 + (idx & 63)];
  }
  if (t < 64) PS[blockIdx.x * 64 + t] = Sred[t];
}

// ---------------------------------------------------------------------------
// Kernel C: kv[bh][d][c] = sum_sp P / sum_sp S[d]
// ---------------------------------------------------------------------------
__global__ __launch_bounds__(256) void ckern(const float* __restrict__ P,
                                             const float* __restrict__ PS,
                                             float* __restrict__ kvb) {
  int bh = blockIdx.x, t = threadIdx.x;
#pragma unroll
  for (int e = 0; e < 16; ++e) {
    int idx = t + e * 256;
    int d = idx >> 6;
    float m = 0.f, s = 0.f;
    for (int sp = 0; sp < 8; ++sp) {
      m += P[(size_t)(bh * 8 + sp) * 4096 + idx];
      s += PS[(bh * 8 + sp) * 64 + d];
    }
    kvb[(size_t)bh * 4096 + idx] = m / s;
  }
}

// ---------------------------------------------------------------------------
// Kernel D1: per 64-row tile, per head: qlog = X@WqT, softmax over kr,
// qkv = softmax(q) @ kv  -- written IN-PLACE over xc rows.
// ---------------------------------------------------------------------------
__global__ __launch_bounds__(256) void d1kern(float* __restrict__ xc,
                                              const float* __restrict__ Wq,
                                              const float* __restrict__ kvb) {
  __shared__ float WqT[64 * 68];
  __shared__ float kvs[64 * 68];
  __shared__ float Xs[64 * 68];
  __shared__ float Et[64 * 68];
  __shared__ float rs[64];
  const int t = threadIdx.x;
  const int tx = t & 15, ty = t >> 4;
  const int row0 = blockIdx.x * 64;
  const int b = row0 >> 14;
  {
    int d4 = (t & 15) * 4;
#pragma unroll
    for (int p = 0; p < 4; ++p) {
      int kr = (t >> 4) + p * 16;
      f4 wq = ldg4(Wq + kr * 64 + d4);
      WqT[(d4 + 0) * 68 + kr] = wq.x; WqT[(d4 + 1) * 68 + kr] = wq.y;
      WqT[(d4 + 2) * 68 + kr] = wq.z; WqT[(d4 + 3) * 68 + kr] = wq.w;
    }
  }
  for (int h = 0; h < 8; ++h) {
    __syncthreads();
#pragma unroll
    for (int p = 0; p < 4; ++p) {
      int lin4 = t + p * 256;
      int d = lin4 >> 4;
      int c = (lin4 & 15) * 4;
      f4 kv = ldg4(kvb + (size_t)(b * 8 + h) * 4096 + lin4 * 4);
      *(f4*)&kvs[d * 68 + c] = kv;
    }
    {
      int d4 = (t & 15) * 4;
#pragma unroll
      for (int p = 0; p < 4; ++p) {
        int r = (t >> 4) + p * 16;
        f4 xv = ldg4(xc + (size_t)(row0 + r) * OCH + h * 64 + d4);
        Xs[(d4 + 0) * 68 + r] = xv.x; Xs[(d4 + 1) * 68 + r] = xv.y;
        Xs[(d4 + 2) * 68 + r] = xv.z; Xs[(d4 + 3) * 68 + r] = xv.w;
      }
    }
    __syncthreads();
    float a1[4][4];
#pragma unroll
    for (int i = 0; i < 4; ++i)
#pragma unroll
      for (int j = 0; j < 4; ++j) a1[i][j] = 0.f;
    const f4* Xs4 = (const f4*)Xs;
    const f4* Wq4 = (const f4*)WqT;
#pragma unroll 8
    for (int k = 0; k < 64; ++k) {
      f4 a = Xs4[k * 17 + ty];
      f4 bq = Wq4[k * 17 + tx];
      float av[4] = {a.x, a.y, a.z, a.w};
      float bv[4] = {bq.x, bq.y, bq.z, bq.w};
#pragma unroll
      for (int i = 0; i < 4; ++i)
#pragma unroll
        for (int j = 0; j < 4; ++j) a1[i][j] = fmaf(av[i], bv[j], a1[i][j]);
    }
#pragma unroll
    for (int i = 0; i < 4; ++i)
#pragma unroll
      for (int j = 0; j < 4; ++j)
        Et[(tx * 4 + j) * 68 + ty * 4 + i] = expf(a1[i][j]);
    __syncthreads();
    if (t < 64) {
      float s = 0.f;
      for (int kr = 0; kr < 64; ++kr) s += Et[kr * 68 + t];
      rs[t] = s;
    }
    __syncthreads();
    float a2[4][4];
#pragma unroll
    for (int i = 0; i < 4; ++i)
#pragma unroll
      for (int j = 0; j < 4; ++j) a2[i][j] = 0.f;
    const f4* Et4 = (const f4*)Et;
    const f4* kv4 = (const f4*)kvs;
#pragma unroll 8
    for (int k = 0; k < 64; ++k) {
      f4 a = Et4[k * 17 + ty];
      f4 bv = kv4[k * 17 + tx];
      float av[4] = {a.x, a.y, a.z, a.w};
      float bb[4] = {bv.x, bv.y, bv.z, bv.w};
#pragma unroll
      for (int i = 0; i < 4; ++i)
#pragma unroll
        for (int j = 0; j < 4; ++j) a2[i][j] = fmaf(av[i], bb[j], a2[i][j]);
    }
#pragma unroll
    for (int i = 0; i < 4; ++i) {
      float inv = 1.0f / rs[ty * 4 + i];
      *(f4*)&xc[(size_t)(row0 + ty * 4 + i) * OCH + h * 64 + tx * 4] =
          make_float4(a2[i][0] * inv, a2[i][1] * inv, a2[i][2] * inv, a2[i][3] * inv);
    }
  }
}

// ---------------------------------------------------------------------------
// Kernel mlp<K,GELU>: Y(row,j) = act(X(row,:) @ W[j,:] + bias[j])
// ---------------------------------------------------------------------------
template <int KTOT, bool DOGELU>
__global__ __launch_bounds__(256) void mlp(const float* __restrict__ X,
                                           const float* __restrict__ W,
                                           const float* __restrict__ bias,
                                           float* __restrict__ Y) {
  __shared__ float Xs[64 * 132];
  __shared__ float Ws[64 * 132];
  const int t = threadIdx.x;
  const int tx = t & 15, ty = t >> 4;
  const int jbase = blockIdx.x * 128;
  const int row0 = blockIdx.y * 128;
  float acc[8][8];
#pragma unroll
  for (int i = 0; i < 8; ++i)
#pragma unroll
    for (int j = 0; j < 8; ++j) acc[i][j] = 0.f;
  const int d4 = (t & 15) * 4;
  for (int kc = 0; kc < KTOT / 64; ++kc) {
    int kb = kc * 64;
    __syncthreads();
#pragma unroll
    for (int p = 0; p < 8; ++p) {
      int r = (t >> 4) + p * 16;
      f4 xv = ldg4(X + (size_t)(row0 + r) * KTOT + kb + d4);
      Xs[(d4 + 0) * 132 + r] = xv.x; Xs[(d4 + 1) * 132 + r] = xv.y;
      Xs[(d4 + 2) * 132 + r] = xv.z; Xs[(d4 + 3) * 132 + r] = xv.w;
    }
#pragma unroll
    for (int p = 0; p < 8; ++p) {
      int jj = (t >> 4) + p * 16;
      f4 wv = ldg4(W + (size_t)(jbase + jj) * KTOT + kb + d4);
      Ws[(d4 + 0) * 132 + jj] = wv.x; Ws[(d4 + 1) * 132 + jj] = wv.y;
      Ws[(d4 + 2) * 132 + jj] = wv.z; Ws[(d4 + 3) * 132 + jj] = wv.w;
    }
    __syncthreads();
    const f4* Xs4 = (const f4*)Xs;
    const f4* Ws4 = (const f4*)Ws;
#pragma unroll 8
    for (int k = 0; k < 64; ++k) {
      f4 a0 = Xs4[k * 33 + ty * 2];
      f4 a1 = Xs4[k * 33 + ty * 2 + 1];
      f4 b0 = Ws4[k * 33 + tx * 2];
      f4 b1 = Ws4[k * 33 + tx * 2 + 1];
      float a[8] = {a0.x, a0.y, a0.z, a0.w, a1.x, a1.y, a1.z, a1.w};
      float b[8] = {b0.x, b0.y, b0.z, b0.w, b1.x, b1.y, b1.z, b1.w};
#pragma unroll
      for (int i = 0; i < 8; ++i)
#pragma unroll
        for (int j = 0; j < 8; ++j) acc[i][j] = fmaf(a[i], b[j], acc[i][j]);
    }
  }
  float bb[8];
#pragma unroll
  for (int j = 0; j < 8; ++j) bb[j] = bias[jbase + tx * 8 + j];
#pragma unroll
  for (int i = 0; i < 8; ++i) {
    int row = row0 + ty * 8 + i;
    float v[8];
#pragma unroll
    for (int j = 0; j < 8; ++j) {
      v[j] = acc[i][j] + bb[j];
      if (DOGELU) v[j] = 0.5f * v[j] * (1.0f + erff(v[j] * 0.70710678118654752440f));
    }
    *(f4*)&Y[(size_t)row * 256 + jbase + tx * 8] = make_float4(v[0], v[1], v[2], v[3]);
    *(f4*)&Y[(size_t)row * 256 + jbase + tx * 8 + 4] = make_float4(v[4], v[5], v[6], v[7]);
  }
}

// ---------------------------------------------------------------------------
extern "C" void kernel_launch(void* const* d_in, const int* in_sizes, int n_in,
                              void* d_out, int out_size, void* d_ws, size_t ws_size,
                              hipStream_t stream) {
  const float* x  = (const float*)d_in[0];
  const float* cw = (const float*)d_in[1];
  const float* cb = (const float*)d_in[2];
  const float* Wq = (const float*)d_in[3];
  const float* Wk = (const float*)d_in[4];
  const float* Wv = (const float*)d_in[5];
  const float* W1 = (const float*)d_in[6];
  const float* b1 = (const float*)d_in[7];
  const float* W2 = (const float*)d_in[8];
  const float* b2 = (const float*)d_in[9];
  float* out = (float*)d_out;
  float* ws = (float*)d_ws;

  // region0 (34,611,200 f32 slots), time-multiplexed:
  //   phase 1 (conv): xp_hi/xp_lo fp16 (8*130*130*256 halfs each)
  //   phase 2 (attn): P (2,097,152) + PS (32,768) + kvb (262,144)
  //   phase 3 (mlp):  y1w (33,554,432)
  _Float16* xph = (_Float16*)ws;
  _Float16* xpl = (_Float16*)(ws + 17305600);
  float* P   = ws;
  float* PS  = ws + 2097152;
  float* kvb = ws + 2129920;
  float* y1w = ws;
  float* xc  = ws + 34611200;              // 67,108,864 f32 (B,N,512)
  _Float16* wh = (_Float16*)(ws + 101720064);  // 1,179,648 halfs
  _Float16* wl = (_Float16*)(ws + 102309888);  // 1,179,648 halfs
  // total: 102,899,712 f32 = 412 MB

  pad_split<<<16900, 256, 0, stream>>>(x, xph, xpl);
  wsplit<<<576, 256, 0, stream>>>(cw, wh, wl);
  conv_mfma<<<4096, 512, 0, stream>>>(xph, xpl, wh, wl, cb, xc);
  bkern<<<512, 256, 0, stream>>>(xc, Wk, Wv, P, PS);
  ckern<<<64, 256, 0, stream>>>(P, PS, kvb);
  d1kern<<<2048, 256, 0, stream>>>(xc, Wq, kvb);
  mlp<512, true><<<dim3(2, 1024), 256, 0, stream>>>(xc, W1, b1, y1w);
  mlp<256, false><<<dim3(2, 1024), 256, 0, stream>>>(y1w, W2, b2, out);
}

// Round 5
// 2701.751 us; speedup vs baseline: 1.2893x; 1.2893x over previous
//
#include <hip/hip_runtime.h>
#include <math.h>

// Problem constants
#define BB 8
#define NN 16384      // H*W = 128*128
#define CCH 256       // input channels
#define OCH 512       // conv output channels = INNER
#define IMG 128

typedef float4 f4;
typedef _Float16 half8 __attribute__((ext_vector_type(8)));
typedef float floatx4 __attribute__((ext_vector_type(4)));

__device__ __forceinline__ f4 ldg4(const float* p) { return *(const f4*)p; }

// async global->LDS, 16B per lane; LDS dest = wave-uniform base + lane*16
__device__ __forceinline__ void gl16(const _Float16* g, const _Float16* l) {
  __builtin_amdgcn_global_load_lds(
      (const __attribute__((address_space(1))) void*)g,
      (__attribute__((address_space(3))) void*)l, 16, 0, 0);
}

// fp16 hi/lo packing helpers (hi = f16(v), lo = f16(v - hi); packed hi|lo<<16)
__device__ __forceinline__ uint32_t packhl(float v) {
  _Float16 h = (_Float16)v;
  _Float16 l = (_Float16)(v - (float)h);
  unsigned short hu, lu;
  __builtin_memcpy(&hu, &h, 2);
  __builtin_memcpy(&lu, &l, 2);
  return (uint32_t)hu | ((uint32_t)lu << 16);
}
__device__ __forceinline__ _Float16 lo16h(uint32_t u) {
  unsigned short s = (unsigned short)(u & 0xffffu);
  _Float16 h; __builtin_memcpy(&h, &s, 2); return h;
}
__device__ __forceinline__ _Float16 hi16h(uint32_t u) {
  unsigned short s = (unsigned short)(u >> 16);
  _Float16 h; __builtin_memcpy(&h, &s, 2); return h;
}
__device__ __forceinline__ void unpack8(uint4 a, uint4 b, half8& hv, half8& lv) {
  uint32_t wv[8] = {a.x, a.y, a.z, a.w, b.x, b.y, b.z, b.w};
#pragma unroll
  for (int j = 0; j < 8; ++j) { hv[j] = lo16h(wv[j]); lv[j] = hi16h(wv[j]); }
}

// ---------------------------------------------------------------------------
// pad_split: x fp32 [8][128][128][256] -> zero-haloed fp16 hi/lo [8][130][130][256]
// ---------------------------------------------------------------------------
__global__ __launch_bounds__(256) void pad_split(const float* __restrict__ x,
                                                 _Float16* __restrict__ xh,
                                                 _Float16* __restrict__ xl) {
  int tid = blockIdx.x * 256 + threadIdx.x;   // 8*130*130*32 = 4,326,400 exact
  int c8 = tid & 31;
  int p = tid >> 5;
  int xcol = p % 130;
  int p2 = p / 130;
  int y = p2 % 130;
  int b = p2 / 130;
  half8 hv, lv;
#pragma unroll
  for (int j = 0; j < 8; ++j) { hv[j] = (_Float16)0.f; lv[j] = (_Float16)0.f; }
  if (y >= 1 && y <= 128 && xcol >= 1 && xcol <= 128) {
    const float* src = x + ((size_t)(b * 128 + y - 1) * 128 + (xcol - 1)) * 256 + c8 * 8;
    f4 v0 = ldg4(src);
    f4 v1 = ldg4(src + 4);
    float vv[8] = {v0.x, v0.y, v0.z, v0.w, v1.x, v1.y, v1.z, v1.w};
#pragma unroll
    for (int j = 0; j < 8; ++j) {
      _Float16 h = (_Float16)vv[j];
      hv[j] = h;
      lv[j] = (_Float16)(vv[j] - (float)h);
    }
  }
  size_t dst = (size_t)p * 256 + c8 * 8;
  *(half8*)(xh + dst) = hv;
  *(half8*)(xl + dst) = lv;
}

// ---------------------------------------------------------------------------
// wsplit: conv_w fp32 [512][256][3][3] -> fp16 hi/lo Bt[tap][o][c] (o-major rows)
// ---------------------------------------------------------------------------
__global__ __launch_bounds__(256) void wsplit(const float* __restrict__ cw,
                                              _Float16* __restrict__ wh,
                                              _Float16* __restrict__ wl) {
  int tid = blockIdx.x * 256 + threadIdx.x;   // 9*512*32 = 147,456 exact
  int c8 = tid & 31;
  int o = (tid >> 5) & 511;
  int tap = tid >> 14;
  half8 hv, lv;
#pragma unroll
  for (int j = 0; j < 8; ++j) {
    float v = cw[(size_t)o * 2304 + (c8 * 8 + j) * 9 + tap];
    _Float16 h = (_Float16)v;
    hv[j] = h;
    lv[j] = (_Float16)(v - (float)h);
  }
  size_t dst = ((size_t)tap * 512 + o) * 256 + c8 * 8;
  *(half8*)(wh + dst) = hv;
  *(half8*)(wl + dst) = lv;
}

// ---------------------------------------------------------------------------
// wsplit_lin: row-major fp32 [rows][K] -> fp16 hi/lo same layout (for W1, W2)
// ---------------------------------------------------------------------------
__global__ __launch_bounds__(256) void wsplit_lin(const float* __restrict__ W,
                                                  _Float16* __restrict__ wh,
                                                  _Float16* __restrict__ wl,
                                                  int n8) {
  int tid = blockIdx.x * 256 + threadIdx.x;
  if (tid >= n8) return;
  const float* src = W + (size_t)tid * 8;
  f4 v0 = ldg4(src);
  f4 v1 = ldg4(src + 4);
  float vv[8] = {v0.x, v0.y, v0.z, v0.w, v1.x, v1.y, v1.z, v1.w};
  half8 hv, lv;
#pragma unroll
  for (int j = 0; j < 8; ++j) {
    _Float16 h = (_Float16)vv[j];
    hv[j] = h;
    lv[j] = (_Float16)(vv[j] - (float)h);
  }
  *(half8*)(wh + (size_t)tid * 8) = hv;
  *(half8*)(wl + (size_t)tid * 8) = lv;
}

// ---------------------------------------------------------------------------
// conv_mfma (round-1 v2, measured best 1297us): 3x3 SAME conv as implicit GEMM
// via fp16x2-split MFMA. Block: 128 pixels x 128 outch. 4 waves, each 64x64.
// 2-phase dbuf schedule + T1 XCD-chunked swizzle. MfmaUtil ~32%; schedule
// variants (depth-2 counted vmcnt, 8-wave) measured WORSE (rounds 3-4).
// ---------------------------------------------------------------------------
__global__ __launch_bounds__(256) void conv_mfma(const _Float16* __restrict__ xph,
                                                 const _Float16* __restrict__ xpl,
                                                 const _Float16* __restrict__ wh,
                                                 const _Float16* __restrict__ wl,
                                                 const float* __restrict__ cb,
                                                 float* __restrict__ xc) {
  __shared__ __align__(16) _Float16 sm[32768];  // 64KB: 2 x (AH AL BH BL @ 4096 halfs each)
  const int t = threadIdx.x;
  const int w = t >> 6, lane = t & 63;
  const int id = blockIdx.x;
  const int swz = (id & 7) * 512 + (id >> 3);
  const int obase = (swz & 3) * 128;
  const int p = swz >> 2;             // 0..1023
  const int bi = p >> 7, yy = p & 127;
  const int wm = (w & 1) * 64, wn = (w >> 1) * 64;

  floatx4 acc[4][4];
#pragma unroll
  for (int i = 0; i < 4; ++i)
#pragma unroll
    for (int j = 0; j < 4; ++j) acc[i][j] = (floatx4){0.f, 0.f, 0.f, 0.f};

  const int g0 = w, g1 = 4 + w;
  const int loff0 = ((g0 & 1) * 64 + lane) * 256 + (g0 >> 1) * 8;
  const int loff1 = ((g1 & 1) * 64 + lane) * 256 + (g1 >> 1) * 8;

  auto stage = [&](int it, _Float16* smb) {
    const int tap = it >> 3;
    const int dy = (tap * 11) >> 5;   // tap/3 for tap in [0,9)
    const int dx = tap - dy * 3;
    const int c0 = (it & 7) * 32;
    const size_t ab = (size_t)((bi * 130 + yy + dy) * 130 + dx) * 256 + c0;
    const size_t bb = (size_t)(tap * 512 + obase) * 256 + c0;
    gl16(xph + ab + loff0, smb + g0 * 512);
    gl16(xph + ab + loff1, smb + g1 * 512);
    gl16(xpl + ab + loff0, smb + 4096 + g0 * 512);
    gl16(xpl + ab + loff1, smb + 4096 + g1 * 512);
    gl16(wh + bb + loff0, smb + 8192 + g0 * 512);
    gl16(wh + bb + loff1, smb + 8192 + g1 * 512);
    gl16(wl + bb + loff0, smb + 12288 + g0 * 512);
    gl16(wl + bb + loff1, smb + 12288 + g1 * 512);
  };

  const int kq = (lane >> 4) * 1024;      // k8 * 128 * 8 halfs
  const int ar = (wm + (lane & 15)) * 8;
  const int br = (wn + (lane & 15)) * 8;

  stage(0, sm);
  asm volatile("s_waitcnt vmcnt(0)" ::: "memory");
  __builtin_amdgcn_s_barrier();

#pragma unroll 2
  for (int it = 0; it < 72; ++it) {
    _Float16* smb = sm + (it & 1) * 16384;
    if (it < 71) stage(it + 1, sm + ((it + 1) & 1) * 16384);

    half8 ah[4], al[4], bh[4], bl[4];
#pragma unroll
    for (int mt = 0; mt < 4; ++mt) {
      ah[mt] = *(const half8*)&smb[kq + ar + mt * 128];
      al[mt] = *(const half8*)&smb[4096 + kq + ar + mt * 128];
    }
#pragma unroll
    for (int nt = 0; nt < 4; ++nt) {
      bh[nt] = *(const half8*)&smb[8192 + kq + br + nt * 128];
      bl[nt] = *(const half8*)&smb[12288 + kq + br + nt * 128];
    }

    __builtin_amdgcn_s_setprio(1);
#pragma unroll
    for (int mt = 0; mt < 4; ++mt)
#pragma unroll
      for (int nt = 0; nt < 4; ++nt) {
        acc[mt][nt] = __builtin_amdgcn_mfma_f32_16x16x32_f16(ah[mt], bh[nt], acc[mt][nt], 0, 0, 0);
        acc[mt][nt] = __builtin_amdgcn_mfma_f32_16x16x32_f16(al[mt], bh[nt], acc[mt][nt], 0, 0, 0);
        acc[mt][nt] = __builtin_amdgcn_mfma_f32_16x16x32_f16(ah[mt], bl[nt], acc[mt][nt], 0, 0, 0);
      }
    __builtin_amdgcn_s_setprio(0);
    __builtin_amdgcn_sched_barrier(0);
    asm volatile("s_waitcnt vmcnt(0)" ::: "memory");
    __builtin_amdgcn_s_barrier();
  }

  const int col = lane & 15;
  const int qr = (lane >> 4) * 4;
#pragma unroll
  for (int nt = 0; nt < 4; ++nt) {
    const int och = obase + wn + nt * 16 + col;
    const float bias = cb[och];
#pragma unroll
    for (int mt = 0; mt < 4; ++mt)
#pragma unroll
      for (int r = 0; r < 4; ++r) {
        int m = wm + mt * 16 + qr + r;
        xc[((size_t)bi * NN + (size_t)yy * IMG + m) * OCH + och] = acc[mt][nt][r] + bias;
      }
  }
}

// ---------------------------------------------------------------------------
// Kernel B: fused K/V projection + kv accumulation (never materializes K,V).
// ---------------------------------------------------------------------------
__global__ __launch_bounds__(256) void bkern(const float* __restrict__ xc,
                                             const float* __restrict__ Wk,
                                             const float* __restrict__ Wv,
                                             float* __restrict__ P,
                                             float* __restrict__ PS) {
  __shared__ float wkT[4096];      // [d][c] = Wk[c][d]
  __shared__ float wvT[4096];
  __shared__ float red[64 * 65];   // block reduce, +1 pad
  __shared__ float Sred[64];
  const int t = threadIdx.x;
  const int bh = blockIdx.x >> 3;
  const int sp = blockIdx.x & 7;
  const int b = bh >> 3, h = bh & 7;
  {
    int d4 = (t & 15) * 4;
#pragma unroll
    for (int p = 0; p < 4; ++p) {
      int kr = (t >> 4) + p * 16;
      f4 wk = ldg4(Wk + kr * 64 + d4);
      f4 wv = ldg4(Wv + kr * 64 + d4);
      wkT[(d4 + 0) * 64 + kr] = wk.x; wkT[(d4 + 1) * 64 + kr] = wk.y;
      wkT[(d4 + 2) * 64 + kr] = wk.z; wkT[(d4 + 3) * 64 + kr] = wk.w;
      wvT[(d4 + 0) * 64 + kr] = wv.x; wvT[(d4 + 1) * 64 + kr] = wv.y;
      wvT[(d4 + 2) * 64 + kr] = wv.z; wvT[(d4 + 3) * 64 + kr] = wv.w;
    }
  }
  __syncthreads();
  const int lane = t & 63, w = t >> 6;
  float macc[64];
#pragma unroll
  for (int d = 0; d < 64; ++d) macc[d] = 0.f;
  float ssum = 0.f;
  const int nbase = sp * 2048 + w * 512;
  const float* xrow = xc + (size_t)(b * NN + nbase) * OCH + h * 64 + lane;
  for (int r = 0; r < 512; ++r) {
    float xv = *xrow;
    xrow += OCH;
    int xi = __float_as_int(xv);
    float klog = 0.f, vv = 0.f;
#pragma unroll
    for (int d = 0; d < 64; ++d) {
      float xd = __int_as_float(__builtin_amdgcn_readlane(xi, d));
      klog = fmaf(xd, wkT[d * 64 + lane], klog);
      vv = fmaf(xd, wvT[d * 64 + lane], vv);
    }
    float ek = expf(klog);
    ssum += ek;
    int ei = __float_as_int(ek);
#pragma unroll
    for (int d = 0; d < 64; ++d) {
      float ekd = __int_as_float(__builtin_amdgcn_readlane(ei, d));
      macc[d] = fmaf(ekd, vv, macc[d]);
    }
  }
  for (int ww = 0; ww < 4; ++ww) {
    if (w == ww) {
      if (ww == 0) {
#pragma unroll
        for (int d = 0; d < 64; ++d) red[d * 65 + lane] = macc[d];
        Sred[lane] = ssum;
      } else {
#pragma unroll
        for (int d = 0; d < 64; ++d) red[d * 65 + lane] += macc[d];
        Sred[lane] += ssum;
      }
    }
    __syncthreads();
  }
  float* Pp = P + (size_t)blockIdx.x * 4096;
#pragma unroll
  for (int e = 0; e < 16; ++e) {
    int idx = t + e * 256;
    Pp[idx] = red[(idx >> 6) * 65 + (idx & 63)];
  }
  if (t < 64) PS[blockIdx.x * 64 + t] = Sred[t];
}

// ---------------------------------------------------------------------------
// Kernel C: kv[bh][d][c] = sum_sp P / sum_sp S[d]
// ---------------------------------------------------------------------------
__global__ __launch_bounds__(256) void ckern(const float* __restrict__ P,
                                             const float* __restrict__ PS,
                                             float* __restrict__ kvb) {
  int bh = blockIdx.x, t = threadIdx.x;
#pragma unroll
  for (int e = 0; e < 16; ++e) {
    int idx = t + e * 256;
    int d = idx >> 6;
    float m = 0.f, s = 0.f;
    for (int sp = 0; sp < 8; ++sp) {
      m += P[(size_t)(bh * 8 + sp) * 4096 + idx];
      s += PS[(bh * 8 + sp) * 64 + d];
    }
    kvb[(size_t)bh * 4096 + idx] = m / s;
  }
}

// ---------------------------------------------------------------------------
// Kernel D1: per 64-row tile, per head: qlog = X@WqT, softmax over kr,
// qkv = softmax(q) @ kv -- written IN-PLACE over xc rows as PACKED fp16 hi/lo
// (hi in bits[15:0], lo in bits[31:16] of the same 4B slot) for mlp_mfma.
// ---------------------------------------------------------------------------
__global__ __launch_bounds__(256) void d1kern(float* __restrict__ xc,
                                              const float* __restrict__ Wq,
                                              const float* __restrict__ kvb) {
  __shared__ float WqT[64 * 68];
  __shared__ float kvs[64 * 68];
  __shared__ float Xs[64 * 68];
  __shared__ float Et[64 * 68];
  __shared__ float rs[64];
  const int t = threadIdx.x;
  const int tx = t & 15, ty = t >> 4;
  const int row0 = blockIdx.x * 64;
  const int b = row0 >> 14;
  {
    int d4 = (t & 15) * 4;
#pragma unroll
    for (int p = 0; p < 4; ++p) {
      int kr = (t >> 4) + p * 16;
      f4 wq = ldg4(Wq + kr * 64 + d4);
      WqT[(d4 + 0) * 68 + kr] = wq.x; WqT[(d4 + 1) * 68 + kr] = wq.y;
      WqT[(d4 + 2) * 68 + kr] = wq.z; WqT[(d4 + 3) * 68 + kr] = wq.w;
    }
  }
  for (int h = 0; h < 8; ++h) {
    __syncthreads();
#pragma unroll
    for (int p = 0; p < 4; ++p) {
      int lin4 = t + p * 256;
      int d = lin4 >> 4;
      int c = (lin4 & 15) * 4;
      f4 kv = ldg4(kvb + (size_t)(b * 8 + h) * 4096 + lin4 * 4);
      *(f4*)&kvs[d * 68 + c] = kv;
    }
    {
      int d4 = (t & 15) * 4;
#pragma unroll
      for (int p = 0; p < 4; ++p) {
        int r = (t >> 4) + p * 16;
        f4 xv = ldg4(xc + (size_t)(row0 + r) * OCH + h * 64 + d4);
        Xs[(d4 + 0) * 68 + r] = xv.x; Xs[(d4 + 1) * 68 + r] = xv.y;
        Xs[(d4 + 2) * 68 + r] = xv.z; Xs[(d4 + 3) * 68 + r] = xv.w;
      }
    }
    __syncthreads();
    float a1[4][4];
#pragma unroll
    for (int i = 0; i < 4; ++i)
#pragma unroll
      for (int j = 0; j < 4; ++j) a1[i][j] = 0.f;
    const f4* Xs4 = (const f4*)Xs;
    const f4* Wq4 = (const f4*)WqT;
#pragma unroll 8
    for (int k = 0; k < 64; ++k) {
      f4 a = Xs4[k * 17 + ty];
      f4 bq = Wq4[k * 17 + tx];
      float av[4] = {a.x, a.y, a.z, a.w};
      float bv[4] = {bq.x, bq.y, bq.z, bq.w};
#pragma unroll
      for (int i = 0; i < 4; ++i)
#pragma unroll
        for (int j = 0; j < 4; ++j) a1[i][j] = fmaf(av[i], bv[j], a1[i][j]);
    }
#pragma unroll
    for (int i = 0; i < 4; ++i)
#pragma unroll
      for (int j = 0; j < 4; ++j)
        Et[(tx * 4 + j) * 68 + ty * 4 + i] = expf(a1[i][j]);
    __syncthreads();
    if (t < 64) {
      float s = 0.f;
      for (int kr = 0; kr < 64; ++kr) s += Et[kr * 68 + t];
      rs[t] = s;
    }
    __syncthreads();
    float a2[4][4];
#pragma unroll
    for (int i = 0; i < 4; ++i)
#pragma unroll
      for (int j = 0; j < 4; ++j) a2[i][j] = 0.f;
    const f4* Et4 = (const f4*)Et;
    const f4* kv4 = (const f4*)kvs;
#pragma unroll 8
    for (int k = 0; k < 64; ++k) {
      f4 a = Et4[k * 17 + ty];
      f4 bv = kv4[k * 17 + tx];
      float av[4] = {a.x, a.y, a.z, a.w};
      float bb[4] = {bv.x, bv.y, bv.z, bv.w};
#pragma unroll
      for (int i = 0; i < 4; ++i)
#pragma unroll
        for (int j = 0; j < 4; ++j) a2[i][j] = fmaf(av[i], bb[j], a2[i][j]);
    }
#pragma unroll
    for (int i = 0; i < 4; ++i) {
      float inv = 1.0f / rs[ty * 4 + i];
      uint32_t pw0 = packhl(a2[i][0] * inv);
      uint32_t pw1 = packhl(a2[i][1] * inv);
      uint32_t pw2 = packhl(a2[i][2] * inv);
      uint32_t pw3 = packhl(a2[i][3] * inv);
      *(uint4*)&((uint32_t*)xc)[(size_t)(row0 + ty * 4 + i) * OCH + h * 64 + tx * 4] =
          make_uint4(pw0, pw1, pw2, pw3);
    }
  }
}

// ---------------------------------------------------------------------------
// mlp_mfma<KTOT,GELU>: Y(row,j) = act(X(row,:) @ W[j,:] + bias[j]) via
// fp16x2-split MFMA (3 terms). X arrives PACKED hi/lo (u32/elem); W pre-split.
// Structure = conv_mfma skeleton: 128 rows x 128 j, 4 waves 64x64, 64KB dbuf,
// 2-phase. B (W) staged via gl16; A (X) reg-staged: loads issued BEFORE the
// MFMA cluster, unpack+ds_write AFTER (T14 issue-early/write-late).
// Output: GELU-> packed hi/lo u32 (for mlp2), else f32.
// ---------------------------------------------------------------------------
template <int KTOT, bool DOGELU>
__global__ __launch_bounds__(256) void mlp_mfma(const uint32_t* __restrict__ Xp,
                                                const _Float16* __restrict__ bwh,
                                                const _Float16* __restrict__ bwl,
                                                const float* __restrict__ bias,
                                                void* __restrict__ Yout) {
  __shared__ __align__(16) _Float16 sm[32768];  // 64KB: 2 x (AH AL BH BL @4096 halfs)
  const int t = threadIdx.x;
  const int w = t >> 6, lane = t & 63;
  const int jbase = blockIdx.x * 128;
  const int row0 = blockIdx.y * 128;
  const int wm = (w & 1) * 64, wn = (w >> 1) * 64;
  constexpr int KS = KTOT / 32;

  floatx4 acc[4][4];
#pragma unroll
  for (int i = 0; i < 4; ++i)
#pragma unroll
    for (int j = 0; j < 4; ++j) acc[i][j] = (floatx4){0.f, 0.f, 0.f, 0.f};

  // B staging slots (gl16): wave w owns g0=w, g1=4+w per matrix
  const int g0 = w, g1 = 4 + w;
  const int loff0 = ((g0 & 1) * 64 + lane) * KTOT + (g0 >> 1) * 8;
  const int loff1 = ((g1 & 1) * 64 + lane) * KTOT + (g1 >> 1) * 8;
  // A reg-staging: thread handles (row=t&127, kk0=t>>7) and (row, kk0+2)
  const int rowA = t & 127, kk0 = t >> 7, kk1 = (t >> 7) + 2;
  const uint32_t* arow = Xp + (size_t)(row0 + rowA) * KTOT;

  const int kq = (lane >> 4) * 1024;
  const int ar = (wm + (lane & 15)) * 8;
  const int br = (wn + (lane & 15)) * 8;

  // prologue: fully stage K-step 0 into buffer 0
  {
    uint4 a0l = *(const uint4*)(arow + kk0 * 8);
    uint4 a0h = *(const uint4*)(arow + kk0 * 8 + 4);
    uint4 a1l = *(const uint4*)(arow + kk1 * 8);
    uint4 a1h = *(const uint4*)(arow + kk1 * 8 + 4);
    const size_t bb = (size_t)jbase * KTOT;
    gl16(bwh + bb + loff0, sm + 8192 + g0 * 512);
    gl16(bwh + bb + loff1, sm + 8192 + g1 * 512);
    gl16(bwl + bb + loff0, sm + 12288 + g0 * 512);
    gl16(bwl + bb + loff1, sm + 12288 + g1 * 512);
    half8 hv, lv;
    unpack8(a0l, a0h, hv, lv);
    *(half8*)&sm[kk0 * 1024 + rowA * 8] = hv;
    *(half8*)&sm[4096 + kk0 * 1024 + rowA * 8] = lv;
    unpack8(a1l, a1h, hv, lv);
    *(half8*)&sm[kk1 * 1024 + rowA * 8] = hv;
    *(half8*)&sm[4096 + kk1 * 1024 + rowA * 8] = lv;
  }
  asm volatile("s_waitcnt vmcnt(0) lgkmcnt(0)" ::: "memory");
  __builtin_amdgcn_s_barrier();

#pragma unroll 2
  for (int kt = 0; kt < KS; ++kt) {
    _Float16* smb = sm + (kt & 1) * 16384;
    _Float16* nbuf = sm + ((kt + 1) & 1) * 16384;
    const bool pre = (kt < KS - 1);
    uint4 a0l, a0h, a1l, a1h;
    if (pre) {
      const int kbn = (kt + 1) * 32;
      a0l = *(const uint4*)(arow + kbn + kk0 * 8);
      a0h = *(const uint4*)(arow + kbn + kk0 * 8 + 4);
      a1l = *(const uint4*)(arow + kbn + kk1 * 8);
      a1h = *(const uint4*)(arow + kbn + kk1 * 8 + 4);
      const size_t bb = (size_t)jbase * KTOT + kbn;
      gl16(bwh + bb + loff0, nbuf + 8192 + g0 * 512);
      gl16(bwh + bb + loff1, nbuf + 8192 + g1 * 512);
      gl16(bwl + bb + loff0, nbuf + 12288 + g0 * 512);
      gl16(bwl + bb + loff1, nbuf + 12288 + g1 * 512);
    }

    half8 ah[4], al[4], bh[4], bl[4];
#pragma unroll
    for (int mt = 0; mt < 4; ++mt) {
      ah[mt] = *(const half8*)&smb[kq + ar + mt * 128];
      al[mt] = *(const half8*)&smb[4096 + kq + ar + mt * 128];
    }
#pragma unroll
    for (int nt = 0; nt < 4; ++nt) {
      bh[nt] = *(const half8*)&smb[8192 + kq + br + nt * 128];
      bl[nt] = *(const half8*)&smb[12288 + kq + br + nt * 128];
    }

    __builtin_amdgcn_s_setprio(1);
#pragma unroll
    for (int mt = 0; mt < 4; ++mt)
#pragma unroll
      for (int nt = 0; nt < 4; ++nt) {
        acc[mt][nt] = __builtin_amdgcn_mfma_f32_16x16x32_f16(ah[mt], bh[nt], acc[mt][nt], 0, 0, 0);
        acc[mt][nt] = __builtin_amdgcn_mfma_f32_16x16x32_f16(al[mt], bh[nt], acc[mt][nt], 0, 0, 0);
        acc[mt][nt] = __builtin_amdgcn_mfma_f32_16x16x32_f16(ah[mt], bl[nt], acc[mt][nt], 0, 0, 0);
      }
    __builtin_amdgcn_s_setprio(0);

    if (pre) {  // unpack + LDS write of next A tile (loads have had MFMA time to land)
      half8 hv, lv;
      unpack8(a0l, a0h, hv, lv);
      *(half8*)&nbuf[kk0 * 1024 + rowA * 8] = hv;
      *(half8*)&nbuf[4096 + kk0 * 1024 + rowA * 8] = lv;
      unpack8(a1l, a1h, hv, lv);
      *(half8*)&nbuf[kk1 * 1024 + rowA * 8] = hv;
      *(half8*)&nbuf[4096 + kk1 * 1024 + rowA * 8] = lv;
    }
    __builtin_amdgcn_sched_barrier(0);
    asm volatile("s_waitcnt vmcnt(0) lgkmcnt(0)" ::: "memory");
    __builtin_amdgcn_s_barrier();
  }

  // epilogue: C/D layout col=lane&15, row=(lane>>4)*4+reg
  const int col = lane & 15;
  const int qr = (lane >> 4) * 4;
#pragma unroll
  for (int nt = 0; nt < 4; ++nt) {
    const int j = jbase + wn + nt * 16 + col;
    const float bj = bias[j];
#pragma unroll
    for (int mt = 0; mt < 4; ++mt)
#pragma unroll
      for (int r = 0; r < 4; ++r) {
        const int row = row0 + wm + mt * 16 + qr + r;
        float v = acc[mt][nt][r] + bj;
        if (DOGELU) {
          v = 0.5f * v * (1.0f + erff(v * 0.70710678118654752440f));
          ((uint32_t*)Yout)[(size_t)row * 256 + j] = packhl(v);
        } else {
          ((float*)Yout)[(size_t)row * 256 + j] = v;
        }
      }
  }
}

// ---------------------------------------------------------------------------
extern "C" void kernel_launch(void* const* d_in, const int* in_sizes, int n_in,
                              void* d_out, int out_size, void* d_ws, size_t ws_size,
                              hipStream_t stream) {
  const float* x  = (const float*)d_in[0];
  const float* cw = (const float*)d_in[1];
  const float* cb = (const float*)d_in[2];
  const float* Wq = (const float*)d_in[3];
  const float* Wk = (const float*)d_in[4];
  const float* Wv = (const float*)d_in[5];
  const float* W1 = (const float*)d_in[6];
  const float* b1 = (const float*)d_in[7];
  const float* W2 = (const float*)d_in[8];
  const float* b2 = (const float*)d_in[9];
  float* out = (float*)d_out;
  float* ws = (float*)d_ws;

  // region0 (34,611,200 f32 slots), time-multiplexed:
  //   phase 1 (conv): xp_hi/xp_lo fp16 (8*130*130*256 halfs each), [0..34.6M)
  //   phase 2 (attn): P (2,097,152) + PS (32,768) + kvb (262,144), [0..2.4M)
  //     + mlp weight splits at [33,554,432..33,751,040) (written post-conv)
  //   phase 3 (mlp):  y1p packed u32 (33,554,432), [0..33.55M)
  _Float16* xph = (_Float16*)ws;
  _Float16* xpl = (_Float16*)(ws + 17305600);
  float* P   = ws;
  float* PS  = ws + 2097152;
  float* kvb = ws + 2129920;
  uint32_t* y1p = (uint32_t*)ws;
  _Float16* mw = (_Float16*)(ws + 33554432);   // 393,216 halfs total
  _Float16* wh1 = mw;                // 256*512
  _Float16* wl1 = mw + 131072;
  _Float16* wh2 = mw + 262144;       // 256*256
  _Float16* wl2 = mw + 327680;
  float* xc  = ws + 34611200;              // 67,108,864 f32 (B,N,512); packed u32 after d1kern
  _Float16* wh = (_Float16*)(ws + 101720064);  // 1,179,648 halfs
  _Float16* wl = (_Float16*)(ws + 102309888);  // 1,179,648 halfs
  // total: 102,899,712 f32 = 412 MB

  pad_split<<<16900, 256, 0, stream>>>(x, xph, xpl);
  wsplit<<<576, 256, 0, stream>>>(cw, wh, wl);
  conv_mfma<<<4096, 256, 0, stream>>>(xph, xpl, wh, wl, cb, xc);
  wsplit_lin<<<64, 256, 0, stream>>>(W1, wh1, wl1, 16384);   // after conv: region0 tail free
  wsplit_lin<<<32, 256, 0, stream>>>(W2, wh2, wl2, 8192);
  bkern<<<512, 256, 0, stream>>>(xc, Wk, Wv, P, PS);
  ckern<<<64, 256, 0, stream>>>(P, PS, kvb);
  d1kern<<<2048, 256, 0, stream>>>(xc, Wq, kvb);
  mlp_mfma<512, true><<<dim3(2, 1024), 256, 0, stream>>>((const uint32_t*)xc, wh1, wl1, b1, y1p);
  mlp_mfma<256, false><<<dim3(2, 1024), 256, 0, stream>>>(y1p, wh2, wl2, b2, out);
}